// Round 1
// baseline (814.612 us; speedup 1.0000x reference)
//
#include <hip/hip_runtime.h>

#define NN 20000
#define EE 320000
#define BB 64
#define DD 256
#define DEPTH 3

// ---------------------------------------------------------------- reductions
__device__ __forceinline__ float blockSum256(float v, float* tmp) {
  #pragma unroll
  for (int o = 32; o > 0; o >>= 1) v += __shfl_down(v, o, 64);
  if ((threadIdx.x & 63) == 0) tmp[threadIdx.x >> 6] = v;
  __syncthreads();
  float r = tmp[0] + tmp[1] + tmp[2] + tmp[3];
  __syncthreads();
  return r;
}

// ---------------------------------------------------------------- M2/M3 precompute
// M2 = W2 @ linW[0:256,:], M3 = W3 @ linW[256:512,:]
__global__ __launch_bounds__(256) void kM(const float* __restrict__ W2,
                                          const float* __restrict__ W3,
                                          const float* __restrict__ linW,
                                          float* __restrict__ M2,
                                          float* __restrict__ M3) {
  int i = blockIdx.x & 255;
  bool second = blockIdx.x >= 256;
  const float* W = second ? W3 : W2;
  const float* L = linW + (second ? DD * DD : 0);
  int j = threadIdx.x;
  float acc = 0.f;
  #pragma unroll 4
  for (int k = 0; k < DD; k++) acc = fmaf(W[i * DD + k], L[k * DD + j], acc);
  (second ? M3 : M2)[i * DD + j] = acc;
}

// ---------------------------------------------------------------- encode
__global__ __launch_bounds__(256) void kEnc(const float* __restrict__ X,
                                            const float* __restrict__ Xs,
                                            const float* __restrict__ W1,
                                            float* __restrict__ h,
                                            float* __restrict__ hs) {
  __shared__ float tmp[4];
  int bid = blockIdx.x, j = threadIdx.x;
  const float* x;
  float* out;
  if (bid < NN) { x = X + (size_t)bid * 2;        out = h  + (size_t)bid * DD; }
  else          { x = Xs + (size_t)(bid - NN) * 2; out = hs + (size_t)(bid - NN) * DD; }
  float v = fmaf(x[0], W1[j], x[1] * W1[DD + j]);
  v = fmaxf(v, 0.f);
  float ss = blockSum256(v * v, tmp);
  float inv = 1.f / fmaxf(sqrtf(ss), 1e-12f);
  out[j] = v * inv;
}

// ---------------------------------------------------------------- CSR build
__global__ __launch_bounds__(256) void kCount(const int* __restrict__ dst,
                                              const int* __restrict__ bassign,
                                              int* cntn, int* cntb) {
  int t = blockIdx.x * 256 + threadIdx.x;
  if (t < EE) atomicAdd(&cntn[dst[t]], 1);
  if (t < NN) atomicAdd(&cntb[bassign[t]], 1);
}

__global__ __launch_bounds__(1024) void kScan(const int* __restrict__ cntn,
                                              int* offn, int* curn,
                                              const int* __restrict__ cntb,
                                              int* offb, int* curb) {
  __shared__ int sums[1024];
  int t = threadIdx.x;
  const int CH = 20;  // 1024*20 = 20480 >= NN
  int base = t * CH;
  int local[CH];
  int s = 0;
  #pragma unroll
  for (int i = 0; i < CH; i++) {
    int idx = base + i;
    int v = (idx < NN) ? cntn[idx] : 0;
    local[i] = s;
    s += v;
  }
  sums[t] = s;
  __syncthreads();
  for (int o = 1; o < 1024; o <<= 1) {
    int x = (t >= o) ? sums[t - o] : 0;
    __syncthreads();
    sums[t] += x;
    __syncthreads();
  }
  int excl = sums[t] - s;
  #pragma unroll
  for (int i = 0; i < CH; i++) {
    int idx = base + i;
    if (idx < NN) {
      int o = excl + local[i];
      offn[idx] = o;
      curn[idx] = o;
    }
  }
  if (t == 1023) offn[NN] = sums[1023];
  __syncthreads();
  if (t == 0) {
    int c = 0;
    for (int i = 0; i < BB; i++) {
      offb[i] = c; curb[i] = c; c += cntb[i];
    }
    offb[BB] = c;
  }
}

__global__ __launch_bounds__(256) void kScatter(const int* __restrict__ src,
                                                const int* __restrict__ dst,
                                                const float* __restrict__ w,
                                                const int* __restrict__ bassign,
                                                int* curn, int* curb,
                                                int* ssrc, float* sw, int* snode) {
  int t = blockIdx.x * 256 + threadIdx.x;
  if (t < EE) {
    int d = dst[t];
    int p = atomicAdd(&curn[d], 1);
    ssrc[p] = src[t];
    sw[p] = w[t];
  }
  if (t < NN) {
    int b = bassign[t];
    int p = atomicAdd(&curb[b], 1);
    snode[p] = t;
  }
}

// ---------------------------------------------------------------- aggregation
__global__ __launch_bounds__(256) void kAgg(const float* __restrict__ h,
                                            const int* __restrict__ offn,
                                            const int* __restrict__ ssrc,
                                            const float* __restrict__ sw,
                                            const int* __restrict__ offb,
                                            const int* __restrict__ snode,
                                            float* __restrict__ hnv,
                                            float* __restrict__ hnvs) {
  int bid = blockIdx.x, j = threadIdx.x;
  if (bid < BB) {  // batch rows first (longest blocks scheduled early)
    int b = bid;
    int s = offb[b], e = offb[b + 1];
    float acc = 0.f;
    int i = s;
    for (; i + 3 < e; i += 4) {
      int n0 = snode[i], n1 = snode[i + 1], n2 = snode[i + 2], n3 = snode[i + 3];
      float v0 = h[(size_t)n0 * DD + j];
      float v1 = h[(size_t)n1 * DD + j];
      float v2 = h[(size_t)n2 * DD + j];
      float v3 = h[(size_t)n3 * DD + j];
      acc += (v0 + v1) + (v2 + v3);
    }
    for (; i < e; i++) acc += h[(size_t)snode[i] * DD + j];
    hnvs[b * DD + j] = acc;
  } else {
    int n = bid - BB;
    int s = offn[n], e = offn[n + 1];
    float acc = 0.f;
    int i = s;
    for (; i + 3 < e; i += 4) {
      int n0 = ssrc[i], n1 = ssrc[i + 1], n2 = ssrc[i + 2], n3 = ssrc[i + 3];
      float w0 = sw[i], w1 = sw[i + 1], w2 = sw[i + 2], w3 = sw[i + 3];
      float v0 = h[(size_t)n0 * DD + j];
      float v1 = h[(size_t)n1 * DD + j];
      float v2 = h[(size_t)n2 * DD + j];
      float v3 = h[(size_t)n3 * DD + j];
      acc += w0 * v0 + w1 * v1 + w2 * v2 + w3 * v3;
    }
    for (; i < e; i++) acc += sw[i] * h[(size_t)ssrc[i] * DD + j];
    hnv[(size_t)n * DD + j] = acc;
  }
}

// ---------------------------------------------------------------- node update GEMM
// out[r, c] = relu( sum_k h[r,k]*M2[k,c] + hnv[r,k]*M3[k,c] + lb[c] )   (pre-norm)
#define TR 128
#define TC 128
#define KB 16
__global__ __launch_bounds__(256) void kUpd(const float* __restrict__ h,
                                            const float* __restrict__ hnv,
                                            const float* __restrict__ M2,
                                            const float* __restrict__ M3,
                                            const float* __restrict__ lb,
                                            float* __restrict__ out) {
  __shared__ __align__(16) float Ah[KB][TR + 4];
  __shared__ __align__(16) float Av[KB][TR + 4];
  __shared__ __align__(16) float Bs2[KB][TC];
  __shared__ __align__(16) float Bs3[KB][TC];
  const int t = threadIdx.x;
  const int rb = blockIdx.x * TR;
  const int cb = blockIdx.y * TC;
  const int tc = t & 15;   // col group: cols cb + tc*8 .. +7
  const int tr = t >> 4;   // row group: rows rb + tr*8 .. +7
  float acc[8][8];
  #pragma unroll
  for (int i = 0; i < 8; i++)
    #pragma unroll
    for (int j = 0; j < 8; j++) acc[i][j] = 0.f;

  for (int k0 = 0; k0 < DD; k0 += KB) {
    // stage A (transposed, k-major)
    #pragma unroll
    for (int it = 0; it < 2; ++it) {
      int idx = t + it * 256;        // 0..511
      int r = idx >> 2;              // 0..127
      int kq = (idx & 3) << 2;       // 0,4,8,12
      int row = rb + r;
      float4 vh = make_float4(0.f, 0.f, 0.f, 0.f), vv = vh;
      if (row < NN) {
        vh = *(const float4*)(h   + (size_t)row * DD + k0 + kq);
        vv = *(const float4*)(hnv + (size_t)row * DD + k0 + kq);
      }
      Ah[kq + 0][r] = vh.x; Ah[kq + 1][r] = vh.y; Ah[kq + 2][r] = vh.z; Ah[kq + 3][r] = vh.w;
      Av[kq + 0][r] = vv.x; Av[kq + 1][r] = vv.y; Av[kq + 2][r] = vv.z; Av[kq + 3][r] = vv.w;
    }
    // stage B
    #pragma unroll
    for (int it = 0; it < 2; ++it) {
      int idx = t + it * 256;        // 0..511
      int kr = idx >> 5;             // 0..15
      int cc = (idx & 31) << 2;      // 0..124
      *(float4*)&Bs2[kr][cc] = *(const float4*)(M2 + (size_t)(k0 + kr) * DD + cb + cc);
      *(float4*)&Bs3[kr][cc] = *(const float4*)(M3 + (size_t)(k0 + kr) * DD + cb + cc);
    }
    __syncthreads();
    #pragma unroll
    for (int k = 0; k < KB; k++) {
      float ah[8], av[8], b2[8], b3[8];
      *(float4*)&ah[0] = *(const float4*)&Ah[k][tr * 8];
      *(float4*)&ah[4] = *(const float4*)&Ah[k][tr * 8 + 4];
      *(float4*)&av[0] = *(const float4*)&Av[k][tr * 8];
      *(float4*)&av[4] = *(const float4*)&Av[k][tr * 8 + 4];
      *(float4*)&b2[0] = *(const float4*)&Bs2[k][tc * 8];
      *(float4*)&b2[4] = *(const float4*)&Bs2[k][tc * 8 + 4];
      *(float4*)&b3[0] = *(const float4*)&Bs3[k][tc * 8];
      *(float4*)&b3[4] = *(const float4*)&Bs3[k][tc * 8 + 4];
      #pragma unroll
      for (int i = 0; i < 8; i++)
        #pragma unroll
        for (int j = 0; j < 8; j++)
          acc[i][j] = fmaf(ah[i], b2[j], fmaf(av[i], b3[j], acc[i][j]));
    }
    __syncthreads();
  }
  // epilogue: bias + relu, store pre-norm
  float bias[8];
  *(float4*)&bias[0] = *(const float4*)(lb + cb + tc * 8);
  *(float4*)&bias[4] = *(const float4*)(lb + cb + tc * 8 + 4);
  #pragma unroll
  for (int i = 0; i < 8; i++) {
    int row = rb + tr * 8 + i;
    if (row < NN) {
      float o[8];
      #pragma unroll
      for (int j = 0; j < 8; j++) o[j] = fmaxf(acc[i][j] + bias[j], 0.f);
      *(float4*)(out + (size_t)row * DD + cb + tc * 8)     = *(float4*)&o[0];
      *(float4*)(out + (size_t)row * DD + cb + tc * 8 + 4) = *(float4*)&o[4];
    }
  }
}

// ---------------------------------------------------------------- row l2norm
__global__ __launch_bounds__(256) void kNorm(const float* __restrict__ in,
                                             float* __restrict__ out) {
  __shared__ float tmp[4];
  int n = blockIdx.x, j = threadIdx.x;
  float v = in[(size_t)n * DD + j];
  float ss = blockSum256(v * v, tmp);
  float inv = 1.f / fmaxf(sqrtf(ss), 1e-12f);
  out[(size_t)n * DD + j] = v * inv;
}

// ---------------------------------------------------------------- state-row update (B=64, in place)
__global__ __launch_bounds__(256) void kUpdS(float* __restrict__ hs,
                                             const float* __restrict__ hnvs,
                                             const float* __restrict__ M2,
                                             const float* __restrict__ M3,
                                             const float* __restrict__ lb) {
  __shared__ float tmp[4];
  __shared__ float rh[DD], rv[DD];
  int b = blockIdx.x, j = threadIdx.x;
  rh[j] = hs[b * DD + j];
  rv[j] = hnvs[b * DD + j];
  __syncthreads();
  float acc = lb[j];
  #pragma unroll 4
  for (int k = 0; k < DD; k++)
    acc = fmaf(rh[k], M2[k * DD + j], fmaf(rv[k], M3[k * DD + j], acc));
  acc = fmaxf(acc, 0.f);
  float ss = blockSum256(acc * acc, tmp);
  float inv = 1.f / fmaxf(sqrtf(ss), 1e-12f);
  hs[b * DD + j] = acc * inv;  // all reads of hs row completed (LDS copy + syncs)
}

// ---------------------------------------------------------------- decode
__global__ __launch_bounds__(256) void kDec(const float* __restrict__ h,
                                            const float* __restrict__ hs,
                                            const int* __restrict__ aidx,
                                            const float* __restrict__ W4,
                                            const float* __restrict__ W5,
                                            float* __restrict__ Q) {
  __shared__ float tmp[4];
  int b = blockIdx.x, j = threadIdx.x;
  float s = blockSum256(hs[b * DD + j] * W4[j], tmp);
  int a = aidx[b];
  float za = h[(size_t)a * DD + j];
  float q = blockSum256(fmaxf(za * s, 0.f) * W5[j], tmp);
  if (j == 0) Q[b] = q;
}

// ---------------------------------------------------------------- launcher
extern "C" void kernel_launch(void* const* d_in, const int* in_sizes, int n_in,
                              void* d_out, int out_size, void* d_ws, size_t ws_size,
                              hipStream_t stream) {
  (void)in_sizes; (void)n_in; (void)out_size; (void)ws_size;
  const int*   edge_src = (const int*)d_in[0];
  const int*   edge_dst = (const int*)d_in[1];
  const float* edge_w   = (const float*)d_in[2];
  const int*   bassign  = (const int*)d_in[3];
  const int*   aidx     = (const int*)d_in[4];
  const float* Xf       = (const float*)d_in[5];
  const float* Xs       = (const float*)d_in[6];
  const float* W1       = (const float*)d_in[7];
  const float* W2       = (const float*)d_in[8];
  const float* W3       = (const float*)d_in[9];
  const float* linW     = (const float*)d_in[10];
  const float* linB     = (const float*)d_in[11];
  const float* W4       = (const float*)d_in[12];
  const float* W5       = (const float*)d_in[13];
  float* Q = (float*)d_out;

  char* base = (char*)d_ws;
  const size_t NB = (size_t)NN * DD * 4;
  float* h    = (float*)(base);
  float* hnv  = (float*)(base + NB);
  float* htmp = (float*)(base + 2 * NB);
  size_t o = 3 * NB;
  float* hs   = (float*)(base + o); o += (size_t)BB * DD * 4;
  float* hnvs = (float*)(base + o); o += (size_t)BB * DD * 4;
  float* M2   = (float*)(base + o); o += (size_t)DD * DD * 4;
  float* M3   = (float*)(base + o); o += (size_t)DD * DD * 4;
  int*   ssrc = (int*)(base + o);   o += (size_t)EE * 4;
  float* swt  = (float*)(base + o); o += (size_t)EE * 4;
  int*   snode= (int*)(base + o);   o += (size_t)NN * 4;
  int*   cntn = (int*)(base + o);   o += (size_t)NN * 4;
  int*   cntb = (int*)(base + o);   o += (size_t)BB * 4;   // contiguous with cntn
  int*   offn = (int*)(base + o);   o += (size_t)(NN + 4) * 4;
  int*   offb = (int*)(base + o);   o += (size_t)(BB + 4) * 4;
  int*   curn = (int*)(base + o);   o += (size_t)NN * 4;
  int*   curb = (int*)(base + o);   o += (size_t)BB * 4;

  hipMemsetAsync(cntn, 0, (size_t)(NN + BB) * 4, stream);

  kM<<<512, 256, 0, stream>>>(W2, W3, linW, M2, M3);
  kEnc<<<NN + BB, 256, 0, stream>>>(Xf, Xs, W1, h, hs);
  kCount<<<(EE + 255) / 256, 256, 0, stream>>>(edge_dst, bassign, cntn, cntb);
  kScan<<<1, 1024, 0, stream>>>(cntn, offn, curn, cntb, offb, curb);
  kScatter<<<(EE + 255) / 256, 256, 0, stream>>>(edge_src, edge_dst, edge_w, bassign,
                                                 curn, curb, ssrc, swt, snode);
  for (int d = 0; d < DEPTH; d++) {
    kAgg<<<NN + BB, 256, 0, stream>>>(h, offn, ssrc, swt, offb, snode, hnv, hnvs);
    kUpd<<<dim3((NN + TR - 1) / TR, DD / TC), 256, 0, stream>>>(h, hnv, M2, M3, linB, htmp);
    kNorm<<<NN, 256, 0, stream>>>(htmp, h);
    kUpdS<<<BB, 256, 0, stream>>>(hs, hnvs, M2, M3, linB);
  }
  kDec<<<BB, 256, 0, stream>>>(h, hs, aidx, W4, W5, Q);
}

// Round 2
// 570.453 us; speedup vs baseline: 1.4280x; 1.4280x over previous
//
#include <hip/hip_runtime.h>

#define NN 20000
#define EE 320000
#define BB 64
#define DD 256
#define DEPTH 3
#define NT (NN + BB)   // h rows + hs rows appended

typedef __attribute__((ext_vector_type(8))) short short8;
typedef __attribute__((ext_vector_type(4))) float floatx4;

// ---------------------------------------------------------------- bf16 split helpers
__device__ __forceinline__ short f2bf(float x) {
  union { float f; unsigned u; } v; v.f = x;
  unsigned r = v.u + 0x7fffu + ((v.u >> 16) & 1u);  // RNE
  return (short)(r >> 16);
}
__device__ __forceinline__ float bf2f(short s) {
  union { unsigned u; float f; } v; v.u = ((unsigned)(unsigned short)s) << 16;
  return v.f;
}

// ---------------------------------------------------------------- reductions
__device__ __forceinline__ float blockSum256(float v, float* tmp) {
  #pragma unroll
  for (int o = 32; o > 0; o >>= 1) v += __shfl_down(v, o, 64);
  if ((threadIdx.x & 63) == 0) tmp[threadIdx.x >> 6] = v;
  __syncthreads();
  float r = tmp[0] + tmp[1] + tmp[2] + tmp[3];
  __syncthreads();
  return r;
}

// ---------------------------------------------------------------- M2/M3 precompute
// M2 = W2 @ linW[0:256,:], M3 = W3 @ linW[256:512,:]
__global__ __launch_bounds__(256) void kM(const float* __restrict__ W2,
                                          const float* __restrict__ W3,
                                          const float* __restrict__ linW,
                                          float* __restrict__ M2,
                                          float* __restrict__ M3) {
  int i = blockIdx.x & 255;
  bool second = blockIdx.x >= 256;
  const float* W = second ? W3 : W2;
  const float* L = linW + (second ? DD * DD : 0);
  int j = threadIdx.x;
  float acc = 0.f;
  #pragma unroll 4
  for (int k = 0; k < DD; k++) acc = fmaf(W[i * DD + k], L[k * DD + j], acc);
  (second ? M3 : M2)[i * DD + j] = acc;
}

// ---------------------------------------------------------------- B' transpose + split
// B'[k][n]: rows 0..255 = M2, 256..511 = M3.  Bt_hi/lo[n][k] bf16, [256][512].
__global__ __launch_bounds__(256) void kBt(const float* __restrict__ M2,
                                           const float* __restrict__ M3,
                                           short* __restrict__ Bth,
                                           short* __restrict__ Btl) {
  int n = blockIdx.x;
  int t = threadIdx.x;
  #pragma unroll
  for (int it = 0; it < 2; it++) {
    int k = t + it * 256;
    float v = (k < DD) ? M2[(size_t)k * DD + n] : M3[(size_t)(k - DD) * DD + n];
    short hi = f2bf(v);
    short lo = f2bf(v - bf2f(hi));
    Bth[(size_t)n * 512 + k] = hi;
    Btl[(size_t)n * 512 + k] = lo;
  }
}

// ---------------------------------------------------------------- encode
__global__ __launch_bounds__(256) void kEnc(const float* __restrict__ X,
                                            const float* __restrict__ Xs,
                                            const float* __restrict__ W1,
                                            float* __restrict__ h) {
  __shared__ float tmp[4];
  int bid = blockIdx.x, j = threadIdx.x;
  const float* x = (bid < NN) ? (X + (size_t)bid * 2) : (Xs + (size_t)(bid - NN) * 2);
  float* out = h + (size_t)bid * DD;
  float v = fmaf(x[0], W1[j], x[1] * W1[DD + j]);
  v = fmaxf(v, 0.f);
  float ss = blockSum256(v * v, tmp);
  float inv = 1.f / fmaxf(sqrtf(ss), 1e-12f);
  out[j] = v * inv;
}

// ---------------------------------------------------------------- CSR build
__global__ __launch_bounds__(256) void kCount(const int* __restrict__ dst,
                                              const int* __restrict__ bassign,
                                              int* cntn, int* cntb) {
  int t = blockIdx.x * 256 + threadIdx.x;
  if (t < EE) atomicAdd(&cntn[dst[t]], 1);
  if (t < NN) atomicAdd(&cntb[bassign[t]], 1);
}

__global__ __launch_bounds__(1024) void kScan(const int* __restrict__ cntn,
                                              int* offn, int* curn,
                                              const int* __restrict__ cntb,
                                              int* offb, int* curb) {
  __shared__ int sums[1024];
  int t = threadIdx.x;
  const int CH = 20;  // 1024*20 = 20480 >= NN
  int base = t * CH;
  int local[CH];
  int s = 0;
  #pragma unroll
  for (int i = 0; i < CH; i++) {
    int idx = base + i;
    int v = (idx < NN) ? cntn[idx] : 0;
    local[i] = s;
    s += v;
  }
  sums[t] = s;
  __syncthreads();
  for (int o = 1; o < 1024; o <<= 1) {
    int x = (t >= o) ? sums[t - o] : 0;
    __syncthreads();
    sums[t] += x;
    __syncthreads();
  }
  int excl = sums[t] - s;
  #pragma unroll
  for (int i = 0; i < CH; i++) {
    int idx = base + i;
    if (idx < NN) {
      int o = excl + local[i];
      offn[idx] = o;
      curn[idx] = o;
    }
  }
  if (t == 1023) offn[NN] = sums[1023];
  __syncthreads();
  if (t == 0) {
    int c = 0;
    for (int i = 0; i < BB; i++) {
      offb[i] = c; curb[i] = c; c += cntb[i];
    }
    offb[BB] = c;
  }
}

__global__ __launch_bounds__(256) void kScatter(const int* __restrict__ src,
                                                const int* __restrict__ dst,
                                                const float* __restrict__ w,
                                                const int* __restrict__ bassign,
                                                int* curn, int* curb,
                                                int* ssrc, float* sw, int* snode) {
  int t = blockIdx.x * 256 + threadIdx.x;
  if (t < EE) {
    int d = dst[t];
    int p = atomicAdd(&curn[d], 1);
    ssrc[p] = src[t];
    sw[p] = w[t];
  }
  if (t < NN) {
    int b = bassign[t];
    int p = atomicAdd(&curb[b], 1);
    snode[p] = t;
  }
}

// ---------------------------------------------------------------- aggregation
// hnv rows 0..NN-1: edge aggregation; rows NN..NN+BB-1: batch aggregation.
__global__ __launch_bounds__(256) void kAgg(const float* __restrict__ h,
                                            const int* __restrict__ offn,
                                            const int* __restrict__ ssrc,
                                            const float* __restrict__ sw,
                                            const int* __restrict__ offb,
                                            const int* __restrict__ snode,
                                            float* __restrict__ hnv) {
  int bid = blockIdx.x, j = threadIdx.x;
  if (bid < BB) {  // batch rows first (longest blocks scheduled early)
    int b = bid;
    int s = offb[b], e = offb[b + 1];
    float acc = 0.f;
    int i = s;
    for (; i + 3 < e; i += 4) {
      int n0 = snode[i], n1 = snode[i + 1], n2 = snode[i + 2], n3 = snode[i + 3];
      float v0 = h[(size_t)n0 * DD + j];
      float v1 = h[(size_t)n1 * DD + j];
      float v2 = h[(size_t)n2 * DD + j];
      float v3 = h[(size_t)n3 * DD + j];
      acc += (v0 + v1) + (v2 + v3);
    }
    for (; i < e; i++) acc += h[(size_t)snode[i] * DD + j];
    hnv[(size_t)(NN + b) * DD + j] = acc;
  } else {
    int n = bid - BB;
    int s = offn[n], e = offn[n + 1];
    float acc = 0.f;
    int i = s;
    for (; i + 3 < e; i += 4) {
      int n0 = ssrc[i], n1 = ssrc[i + 1], n2 = ssrc[i + 2], n3 = ssrc[i + 3];
      float w0 = sw[i], w1 = sw[i + 1], w2 = sw[i + 2], w3 = sw[i + 3];
      float v0 = h[(size_t)n0 * DD + j];
      float v1 = h[(size_t)n1 * DD + j];
      float v2 = h[(size_t)n2 * DD + j];
      float v3 = h[(size_t)n3 * DD + j];
      acc += w0 * v0 + w1 * v1 + w2 * v2 + w3 * v3;
    }
    for (; i < e; i++) acc += sw[i] * h[(size_t)ssrc[i] * DD + j];
    hnv[(size_t)n * DD + j] = acc;
  }
}

// ---------------------------------------------------------------- MFMA dual-GEMM (split-bf16, 3-pass)
// out[r,c] = relu( sum_k A'[r,k]*B'[k,c] + lb[c] ), A' = [h | hnv] (K=512).
// Tile: 128 rows x 128 cols per block (4 waves, 64x64 each), KC=32.
#define TRU 128
#define TCU 128
#define KC 32
__global__ __launch_bounds__(256) void kUpdM(const float* __restrict__ A,
                                             const float* __restrict__ Av,
                                             const short* __restrict__ Bth,
                                             const short* __restrict__ Btl,
                                             const float* __restrict__ lb,
                                             float* __restrict__ out) {
  __shared__ __align__(16) short Ah[TRU][KC];
  __shared__ __align__(16) short Al[TRU][KC];
  __shared__ __align__(16) short Bh[TCU][KC];
  __shared__ __align__(16) short Bl[TCU][KC];
  const int t = threadIdx.x;
  const int rb = blockIdx.x * TRU;
  const int cb = blockIdx.y * TCU;
  const int wid = t >> 6;
  const int lane = t & 63;
  const int wr = (wid & 1) * 64;   // wave row offset in block tile
  const int wc = (wid >> 1) * 64;  // wave col offset
  const int m16 = lane & 15;
  const int kg = lane >> 4;        // 0..3

  floatx4 acc[4][4];
  #pragma unroll
  for (int ct = 0; ct < 4; ct++) {
    float b = lb[cb + wc + ct * 16 + m16];
    #pragma unroll
    for (int rt = 0; rt < 4; rt++) acc[rt][ct] = (floatx4){b, b, b, b};
  }

  for (int kc = 0; kc < 512 / KC; ++kc) {
    const int k0 = kc * KC;
    const float* src = (k0 < DD) ? (A + k0) : (Av + (k0 - DD));
    // ---- stage A (fp32 -> hi/lo bf16), 128 rows x 32 k
    #pragma unroll
    for (int it = 0; it < 4; ++it) {
      int idx = t + it * 256;        // 0..1023
      int r = idx >> 3;              // 0..127
      int q = idx & 7;               // float4 index within row
      int row = rb + r;
      float4 v = make_float4(0.f, 0.f, 0.f, 0.f);
      if (row < NT) v = *(const float4*)(src + (size_t)row * DD + q * 4);
      short s0 = f2bf(v.x), s1 = f2bf(v.y), s2 = f2bf(v.z), s3 = f2bf(v.w);
      short l0 = f2bf(v.x - bf2f(s0)), l1 = f2bf(v.y - bf2f(s1));
      short l2 = f2bf(v.z - bf2f(s2)), l3 = f2bf(v.w - bf2f(s3));
      uint2 whi, wlo;
      whi.x = (unsigned short)s0 | ((unsigned)(unsigned short)s1 << 16);
      whi.y = (unsigned short)s2 | ((unsigned)(unsigned short)s3 << 16);
      wlo.x = (unsigned short)l0 | ((unsigned)(unsigned short)l1 << 16);
      wlo.y = (unsigned short)l2 | ((unsigned)(unsigned short)l3 << 16);
      *(uint2*)&Ah[r][q * 4] = whi;
      *(uint2*)&Al[r][q * 4] = wlo;
    }
    // ---- stage B (pre-split bf16, straight copy), 128 n x 32 k
    #pragma unroll
    for (int it = 0; it < 2; ++it) {
      int idx = t + it * 256;        // 0..511
      int n = idx >> 2;              // 0..127
      int sg = idx & 3;              // 16B segment
      const uint4* ph = (const uint4*)(Bth + (size_t)(cb + n) * 512 + k0) + sg;
      const uint4* pl = (const uint4*)(Btl + (size_t)(cb + n) * 512 + k0) + sg;
      *(uint4*)&Bh[n][sg * 8] = *ph;
      *(uint4*)&Bl[n][sg * 8] = *pl;
    }
    __syncthreads();
    // ---- fragments + MFMA
    short8 af[4], al_[4], bf_[4], bl_[4];
    #pragma unroll
    for (int rt = 0; rt < 4; rt++) {
      af[rt]  = *(const short8*)&Ah[wr + rt * 16 + m16][kg * 8];
      al_[rt] = *(const short8*)&Al[wr + rt * 16 + m16][kg * 8];
    }
    #pragma unroll
    for (int ct = 0; ct < 4; ct++) {
      bf_[ct] = *(const short8*)&Bh[wc + ct * 16 + m16][kg * 8];
      bl_[ct] = *(const short8*)&Bl[wc + ct * 16 + m16][kg * 8];
    }
    #pragma unroll
    for (int rt = 0; rt < 4; rt++)
      #pragma unroll
      for (int ct = 0; ct < 4; ct++) {
        acc[rt][ct] = __builtin_amdgcn_mfma_f32_16x16x32_bf16(af[rt], bf_[ct], acc[rt][ct], 0, 0, 0);
        acc[rt][ct] = __builtin_amdgcn_mfma_f32_16x16x32_bf16(af[rt], bl_[ct], acc[rt][ct], 0, 0, 0);
        acc[rt][ct] = __builtin_amdgcn_mfma_f32_16x16x32_bf16(al_[rt], bf_[ct], acc[rt][ct], 0, 0, 0);
      }
    __syncthreads();
  }
  // ---- epilogue: relu + store (C/D: col=lane&15, row=(lane>>4)*4+reg)
  #pragma unroll
  for (int rt = 0; rt < 4; rt++) {
    #pragma unroll
    for (int ct = 0; ct < 4; ct++) {
      int col = cb + wc + ct * 16 + m16;
      int row0 = rb + wr + rt * 16 + kg * 4;
      #pragma unroll
      for (int reg = 0; reg < 4; reg++) {
        int row = row0 + reg;
        if (row < NT) out[(size_t)row * DD + col] = fmaxf(acc[rt][ct][reg], 0.f);
      }
    }
  }
}

// ---------------------------------------------------------------- row l2norm
__global__ __launch_bounds__(256) void kNorm(const float* __restrict__ in,
                                             float* __restrict__ out) {
  __shared__ float tmp[4];
  int n = blockIdx.x, j = threadIdx.x;
  float v = in[(size_t)n * DD + j];
  float ss = blockSum256(v * v, tmp);
  float inv = 1.f / fmaxf(sqrtf(ss), 1e-12f);
  out[(size_t)n * DD + j] = v * inv;
}

// ---------------------------------------------------------------- decode
__global__ __launch_bounds__(256) void kDec(const float* __restrict__ h,
                                            const int* __restrict__ aidx,
                                            const float* __restrict__ W4,
                                            const float* __restrict__ W5,
                                            float* __restrict__ Q) {
  __shared__ float tmp[4];
  int b = blockIdx.x, j = threadIdx.x;
  float s = blockSum256(h[(size_t)(NN + b) * DD + j] * W4[j], tmp);
  int a = aidx[b];
  float za = h[(size_t)a * DD + j];
  float q = blockSum256(fmaxf(za * s, 0.f) * W5[j], tmp);
  if (j == 0) Q[b] = q;
}

// ---------------------------------------------------------------- launcher
extern "C" void kernel_launch(void* const* d_in, const int* in_sizes, int n_in,
                              void* d_out, int out_size, void* d_ws, size_t ws_size,
                              hipStream_t stream) {
  (void)in_sizes; (void)n_in; (void)out_size; (void)ws_size;
  const int*   edge_src = (const int*)d_in[0];
  const int*   edge_dst = (const int*)d_in[1];
  const float* edge_w   = (const float*)d_in[2];
  const int*   bassign  = (const int*)d_in[3];
  const int*   aidx     = (const int*)d_in[4];
  const float* Xf       = (const float*)d_in[5];
  const float* Xs       = (const float*)d_in[6];
  const float* W1       = (const float*)d_in[7];
  const float* W2       = (const float*)d_in[8];
  const float* W3       = (const float*)d_in[9];
  const float* linW     = (const float*)d_in[10];
  const float* linB     = (const float*)d_in[11];
  const float* W4       = (const float*)d_in[12];
  const float* W5       = (const float*)d_in[13];
  float* Q = (float*)d_out;

  char* base = (char*)d_ws;
  const size_t NB = (size_t)NT * DD * 4;   // rows include hs
  float* h    = (float*)(base);
  float* hnv  = (float*)(base + NB);
  float* htmp = (float*)(base + 2 * NB);
  size_t o = 3 * NB;
  float* M2   = (float*)(base + o); o += (size_t)DD * DD * 4;
  float* M3   = (float*)(base + o); o += (size_t)DD * DD * 4;
  short* Bth  = (short*)(base + o); o += (size_t)DD * 512 * 2;
  short* Btl  = (short*)(base + o); o += (size_t)DD * 512 * 2;
  int*   ssrc = (int*)(base + o);   o += (size_t)EE * 4;
  float* swt  = (float*)(base + o); o += (size_t)EE * 4;
  int*   snode= (int*)(base + o);   o += (size_t)NN * 4;
  int*   cntn = (int*)(base + o);   o += (size_t)NN * 4;
  int*   cntb = (int*)(base + o);   o += (size_t)BB * 4;   // contiguous with cntn
  int*   offn = (int*)(base + o);   o += (size_t)(NN + 4) * 4;
  int*   offb = (int*)(base + o);   o += (size_t)(BB + 4) * 4;
  int*   curn = (int*)(base + o);   o += (size_t)NN * 4;
  int*   curb = (int*)(base + o);   o += (size_t)BB * 4;

  hipMemsetAsync(cntn, 0, (size_t)(NN + BB) * 4, stream);

  kM<<<512, 256, 0, stream>>>(W2, W3, linW, M2, M3);
  kBt<<<DD, 256, 0, stream>>>(M2, M3, Bth, Btl);
  kEnc<<<NT, 256, 0, stream>>>(Xf, Xs, W1, h);
  kCount<<<(EE + 255) / 256, 256, 0, stream>>>(edge_dst, bassign, cntn, cntb);
  kScan<<<1, 1024, 0, stream>>>(cntn, offn, curn, cntb, offb, curb);
  kScatter<<<(EE + 255) / 256, 256, 0, stream>>>(edge_src, edge_dst, edge_w, bassign,
                                                 curn, curb, ssrc, swt, snode);
  for (int d = 0; d < DEPTH; d++) {
    kAgg<<<NN + BB, 256, 0, stream>>>(h, offn, ssrc, swt, offb, snode, hnv);
    kUpdM<<<dim3((NT + TRU - 1) / TRU, DD / TCU), 256, 0, stream>>>(h, hnv, Bth, Btl, linB, htmp);
    kNorm<<<NT, 256, 0, stream>>>(htmp, h);
  }
  kDec<<<BB, 256, 0, stream>>>(h, aidx, W4, W5, Q);
}

// Round 3
// 510.998 us; speedup vs baseline: 1.5942x; 1.1164x over previous
//
#include <hip/hip_runtime.h>

#define NN 20000
#define EE 320000
#define BB 64
#define DD 256
#define DEPTH 3
#define NT (NN + BB)   // h rows + hs rows appended

typedef __attribute__((ext_vector_type(8))) short short8;
typedef __attribute__((ext_vector_type(4))) float floatx4;

// ---------------------------------------------------------------- bf16 split helpers
__device__ __forceinline__ short f2bf(float x) {
  union { float f; unsigned u; } v; v.f = x;
  unsigned r = v.u + 0x7fffu + ((v.u >> 16) & 1u);  // RNE
  return (short)(r >> 16);
}
__device__ __forceinline__ float bf2f(short s) {
  union { unsigned u; float f; } v; v.u = ((unsigned)(unsigned short)s) << 16;
  return v.f;
}

// ---------------------------------------------------------------- reductions
__device__ __forceinline__ float blockSum256(float v, float* tmp) {
  #pragma unroll
  for (int o = 32; o > 0; o >>= 1) v += __shfl_down(v, o, 64);
  if ((threadIdx.x & 63) == 0) tmp[threadIdx.x >> 6] = v;
  __syncthreads();
  float r = tmp[0] + tmp[1] + tmp[2] + tmp[3];
  __syncthreads();
  return r;
}

// ---------------------------------------------------------------- M2/M3 -> split transposed B
// M2 = W2 @ linW[0:256,:], M3 = W3 @ linW[256:512,:]
// B'[k][n]: rows 0..255 = M2, 256..511 = M3. Stored as Bt_hi/lo[n][k] bf16 [256][512].
__global__ __launch_bounds__(256) void kM(const float* __restrict__ W2,
                                          const float* __restrict__ W3,
                                          const float* __restrict__ linW,
                                          short* __restrict__ Bth,
                                          short* __restrict__ Btl) {
  int i = blockIdx.x & 255;
  bool second = blockIdx.x >= 256;
  const float* W = second ? W3 : W2;
  const float* L = linW + (second ? DD * DD : 0);
  int j = threadIdx.x;
  float acc = 0.f;
  #pragma unroll 4
  for (int k = 0; k < DD; k++) acc = fmaf(W[i * DD + k], L[k * DD + j], acc);
  short hi = f2bf(acc);
  short lo = f2bf(acc - bf2f(hi));
  int kk = second ? (DD + i) : i;
  Bth[(size_t)j * 512 + kk] = hi;
  Btl[(size_t)j * 512 + kk] = lo;
}

// ---------------------------------------------------------------- encode + degree count (fused)
__global__ __launch_bounds__(256) void kEncCount(const float* __restrict__ X,
                                                 const float* __restrict__ Xs,
                                                 const float* __restrict__ W1,
                                                 float* __restrict__ h,
                                                 const int* __restrict__ dst,
                                                 const int* __restrict__ bassign,
                                                 int* cntn, int* cntb) {
  __shared__ float tmp[4];
  int bid = blockIdx.x, j = threadIdx.x;
  if (bid < NT) {
    const float* x = (bid < NN) ? (X + (size_t)bid * 2) : (Xs + (size_t)(bid - NN) * 2);
    float* out = h + (size_t)bid * DD;
    float v = fmaf(x[0], W1[j], x[1] * W1[DD + j]);
    v = fmaxf(v, 0.f);
    float ss = blockSum256(v * v, tmp);
    float inv = 1.f / fmaxf(sqrtf(ss), 1e-12f);
    out[j] = v * inv;
  } else {
    int t = (bid - NT) * 256 + j;
    if (t < EE) atomicAdd(&cntn[dst[t]], 1);
    if (t < NN) atomicAdd(&cntb[bassign[t]], 1);
  }
}

// ---------------------------------------------------------------- CSR scan
__global__ __launch_bounds__(1024) void kScan(const int* __restrict__ cntn,
                                              int* offn, int* curn,
                                              const int* __restrict__ cntb,
                                              int* offb, int* curb) {
  __shared__ int sums[1024];
  int t = threadIdx.x;
  const int CH = 20;  // 1024*20 = 20480 >= NN
  int base = t * CH;
  int local[CH];
  int s = 0;
  #pragma unroll
  for (int i = 0; i < CH; i++) {
    int idx = base + i;
    int v = (idx < NN) ? cntn[idx] : 0;
    local[i] = s;
    s += v;
  }
  sums[t] = s;
  __syncthreads();
  for (int o = 1; o < 1024; o <<= 1) {
    int x = (t >= o) ? sums[t - o] : 0;
    __syncthreads();
    sums[t] += x;
    __syncthreads();
  }
  int excl = sums[t] - s;
  #pragma unroll
  for (int i = 0; i < CH; i++) {
    int idx = base + i;
    if (idx < NN) {
      int o = excl + local[i];
      offn[idx] = o;
      curn[idx] = o;
    }
  }
  if (t == 1023) offn[NN] = sums[1023];
  // batch offsets: 64-lane shuffle scan (first wave)
  if (t < 64) {
    int v = cntb[t];
    int incl = v;
    #pragma unroll
    for (int o = 1; o < 64; o <<= 1) {
      int x = __shfl_up(incl, o, 64);
      if (t >= o) incl += x;
    }
    int excl2 = incl - v;
    offb[t] = excl2;
    curb[t] = excl2;
    if (t == 63) offb[BB] = incl;
  }
}

__global__ __launch_bounds__(256) void kScatter(const int* __restrict__ src,
                                                const int* __restrict__ dst,
                                                const float* __restrict__ w,
                                                const int* __restrict__ bassign,
                                                int* curn, int* curb,
                                                int* ssrc, float* sw, int* snode) {
  int t = blockIdx.x * 256 + threadIdx.x;
  if (t < EE) {
    int d = dst[t];
    int p = atomicAdd(&curn[d], 1);
    ssrc[p] = src[t];
    sw[p] = w[t];
  }
  if (t < NN) {
    int b = bassign[t];
    int p = atomicAdd(&curb[b], 1);
    snode[p] = t;
  }
}

// ---------------------------------------------------------------- aggregation
// hnv rows 0..NN-1: edge aggregation; rows NN..NN+BB-1: batch aggregation.
__global__ __launch_bounds__(256) void kAgg(const float* __restrict__ h,
                                            const int* __restrict__ offn,
                                            const int* __restrict__ ssrc,
                                            const float* __restrict__ sw,
                                            const int* __restrict__ offb,
                                            const int* __restrict__ snode,
                                            float* __restrict__ hnv) {
  int bid = blockIdx.x, j = threadIdx.x;
  if (bid < BB) {  // batch rows first (longest blocks scheduled early)
    int b = bid;
    int s = offb[b], e = offb[b + 1];
    float acc = 0.f;
    int i = s;
    for (; i + 3 < e; i += 4) {
      int n0 = snode[i], n1 = snode[i + 1], n2 = snode[i + 2], n3 = snode[i + 3];
      float v0 = h[(size_t)n0 * DD + j];
      float v1 = h[(size_t)n1 * DD + j];
      float v2 = h[(size_t)n2 * DD + j];
      float v3 = h[(size_t)n3 * DD + j];
      acc += (v0 + v1) + (v2 + v3);
    }
    for (; i < e; i++) acc += h[(size_t)snode[i] * DD + j];
    hnv[(size_t)(NN + b) * DD + j] = acc;
  } else {
    int n = bid - BB;
    int s = offn[n], e = offn[n + 1];
    float acc = 0.f;
    int i = s;
    for (; i + 3 < e; i += 4) {
      int n0 = ssrc[i], n1 = ssrc[i + 1], n2 = ssrc[i + 2], n3 = ssrc[i + 3];
      float w0 = sw[i], w1 = sw[i + 1], w2 = sw[i + 2], w3 = sw[i + 3];
      float v0 = h[(size_t)n0 * DD + j];
      float v1 = h[(size_t)n1 * DD + j];
      float v2 = h[(size_t)n2 * DD + j];
      float v3 = h[(size_t)n3 * DD + j];
      acc += w0 * v0 + w1 * v1 + w2 * v2 + w3 * v3;
    }
    for (; i < e; i++) acc += sw[i] * h[(size_t)ssrc[i] * DD + j];
    hnv[(size_t)n * DD + j] = acc;
  }
}

// ---------------------------------------------------------------- MFMA dual-GEMM (split-bf16, 3-pass)
// out[r,c] = relu( sum_k A'[r,k]*B'[k,c] + lb[c] ), A' = [h | hnv] (K=512).
// Tile: 64 rows x 128 cols per block (4 waves, 32x64 each), KC=32 -> grid 314x2=628 blocks.
#define TRU 64
#define TCU 128
#define KC 32
__global__ __launch_bounds__(256) void kUpdM(const float* __restrict__ A,
                                             const float* __restrict__ Av,
                                             const short* __restrict__ Bth,
                                             const short* __restrict__ Btl,
                                             const float* __restrict__ lb,
                                             float* __restrict__ out) {
  __shared__ __align__(16) short Ah[TRU][KC];
  __shared__ __align__(16) short Al[TRU][KC];
  __shared__ __align__(16) short Bh[TCU][KC];
  __shared__ __align__(16) short Bl[TCU][KC];
  const int t = threadIdx.x;
  const int rb = blockIdx.x * TRU;
  const int cb = blockIdx.y * TCU;
  const int wid = t >> 6;
  const int lane = t & 63;
  const int wr = (wid & 1) * 32;   // wave row offset in block tile
  const int wc = (wid >> 1) * 64;  // wave col offset
  const int m16 = lane & 15;
  const int kg = lane >> 4;        // 0..3

  floatx4 acc[2][4];
  #pragma unroll
  for (int ct = 0; ct < 4; ct++) {
    float b = lb[cb + wc + ct * 16 + m16];
    #pragma unroll
    for (int rt = 0; rt < 2; rt++) acc[rt][ct] = (floatx4){b, b, b, b};
  }

  for (int kc = 0; kc < 512 / KC; ++kc) {
    const int k0 = kc * KC;
    const float* src = (k0 < DD) ? (A + k0) : (Av + (k0 - DD));
    // ---- stage A (fp32 -> hi/lo bf16), 64 rows x 32 k = 512 float4
    #pragma unroll
    for (int it = 0; it < 2; ++it) {
      int idx = t + it * 256;        // 0..511
      int r = idx >> 3;              // 0..63
      int q = idx & 7;               // float4 index within row
      int row = rb + r;
      float4 v = make_float4(0.f, 0.f, 0.f, 0.f);
      if (row < NT) v = *(const float4*)(src + (size_t)row * DD + q * 4);
      short s0 = f2bf(v.x), s1 = f2bf(v.y), s2 = f2bf(v.z), s3 = f2bf(v.w);
      short l0 = f2bf(v.x - bf2f(s0)), l1 = f2bf(v.y - bf2f(s1));
      short l2 = f2bf(v.z - bf2f(s2)), l3 = f2bf(v.w - bf2f(s3));
      uint2 whi, wlo;
      whi.x = (unsigned short)s0 | ((unsigned)(unsigned short)s1 << 16);
      whi.y = (unsigned short)s2 | ((unsigned)(unsigned short)s3 << 16);
      wlo.x = (unsigned short)l0 | ((unsigned)(unsigned short)l1 << 16);
      wlo.y = (unsigned short)l2 | ((unsigned)(unsigned short)l3 << 16);
      *(uint2*)&Ah[r][q * 4] = whi;
      *(uint2*)&Al[r][q * 4] = wlo;
    }
    // ---- stage B (pre-split bf16, straight copy), 128 n x 32 k
    #pragma unroll
    for (int it = 0; it < 2; ++it) {
      int idx = t + it * 256;        // 0..511
      int n = idx >> 2;              // 0..127
      int sg = idx & 3;              // 16B segment
      const uint4* ph = (const uint4*)(Bth + (size_t)(cb + n) * 512 + k0) + sg;
      const uint4* pl = (const uint4*)(Btl + (size_t)(cb + n) * 512 + k0) + sg;
      *(uint4*)&Bh[n][sg * 8] = *ph;
      *(uint4*)&Bl[n][sg * 8] = *pl;
    }
    __syncthreads();
    // ---- fragments + MFMA
    short8 af[2], al_[2], bf_[4], bl_[4];
    #pragma unroll
    for (int rt = 0; rt < 2; rt++) {
      af[rt]  = *(const short8*)&Ah[wr + rt * 16 + m16][kg * 8];
      al_[rt] = *(const short8*)&Al[wr + rt * 16 + m16][kg * 8];
    }
    #pragma unroll
    for (int ct = 0; ct < 4; ct++) {
      bf_[ct] = *(const short8*)&Bh[wc + ct * 16 + m16][kg * 8];
      bl_[ct] = *(const short8*)&Bl[wc + ct * 16 + m16][kg * 8];
    }
    #pragma unroll
    for (int rt = 0; rt < 2; rt++)
      #pragma unroll
      for (int ct = 0; ct < 4; ct++) {
        acc[rt][ct] = __builtin_amdgcn_mfma_f32_16x16x32_bf16(af[rt], bf_[ct], acc[rt][ct], 0, 0, 0);
        acc[rt][ct] = __builtin_amdgcn_mfma_f32_16x16x32_bf16(af[rt], bl_[ct], acc[rt][ct], 0, 0, 0);
        acc[rt][ct] = __builtin_amdgcn_mfma_f32_16x16x32_bf16(al_[rt], bf_[ct], acc[rt][ct], 0, 0, 0);
      }
    __syncthreads();
  }
  // ---- epilogue: relu + store (C/D: col=lane&15, row=(lane>>4)*4+reg)
  #pragma unroll
  for (int rt = 0; rt < 2; rt++) {
    #pragma unroll
    for (int ct = 0; ct < 4; ct++) {
      int col = cb + wc + ct * 16 + m16;
      int row0 = rb + wr + rt * 16 + kg * 4;
      #pragma unroll
      for (int reg = 0; reg < 4; reg++) {
        int row = row0 + reg;
        if (row < NT) out[(size_t)row * DD + col] = fmaxf(acc[rt][ct][reg], 0.f);
      }
    }
  }
}

// ---------------------------------------------------------------- row l2norm
__global__ __launch_bounds__(256) void kNorm(const float* __restrict__ in,
                                             float* __restrict__ out) {
  __shared__ float tmp[4];
  int n = blockIdx.x, j = threadIdx.x;
  float v = in[(size_t)n * DD + j];
  float ss = blockSum256(v * v, tmp);
  float inv = 1.f / fmaxf(sqrtf(ss), 1e-12f);
  out[(size_t)n * DD + j] = v * inv;
}

// ---------------------------------------------------------------- decode
__global__ __launch_bounds__(256) void kDec(const float* __restrict__ h,
                                            const int* __restrict__ aidx,
                                            const float* __restrict__ W4,
                                            const float* __restrict__ W5,
                                            float* __restrict__ Q) {
  __shared__ float tmp[4];
  int b = blockIdx.x, j = threadIdx.x;
  float s = blockSum256(h[(size_t)(NN + b) * DD + j] * W4[j], tmp);
  int a = aidx[b];
  float za = h[(size_t)a * DD + j];
  float q = blockSum256(fmaxf(za * s, 0.f) * W5[j], tmp);
  if (j == 0) Q[b] = q;
}

// ---------------------------------------------------------------- launcher
extern "C" void kernel_launch(void* const* d_in, const int* in_sizes, int n_in,
                              void* d_out, int out_size, void* d_ws, size_t ws_size,
                              hipStream_t stream) {
  (void)in_sizes; (void)n_in; (void)out_size; (void)ws_size;
  const int*   edge_src = (const int*)d_in[0];
  const int*   edge_dst = (const int*)d_in[1];
  const float* edge_w   = (const float*)d_in[2];
  const int*   bassign  = (const int*)d_in[3];
  const int*   aidx     = (const int*)d_in[4];
  const float* Xf       = (const float*)d_in[5];
  const float* Xs       = (const float*)d_in[6];
  const float* W1       = (const float*)d_in[7];
  const float* W2       = (const float*)d_in[8];
  const float* W3       = (const float*)d_in[9];
  const float* linW     = (const float*)d_in[10];
  const float* linB     = (const float*)d_in[11];
  const float* W4       = (const float*)d_in[12];
  const float* W5       = (const float*)d_in[13];
  float* Q = (float*)d_out;

  char* base = (char*)d_ws;
  const size_t NB = (size_t)NT * DD * 4;   // rows include hs
  float* h    = (float*)(base);
  float* hnv  = (float*)(base + NB);
  float* htmp = (float*)(base + 2 * NB);
  size_t o = 3 * NB;
  short* Bth  = (short*)(base + o); o += (size_t)DD * 512 * 2;
  short* Btl  = (short*)(base + o); o += (size_t)DD * 512 * 2;
  int*   ssrc = (int*)(base + o);   o += (size_t)EE * 4;
  float* swt  = (float*)(base + o); o += (size_t)EE * 4;
  int*   snode= (int*)(base + o);   o += (size_t)NN * 4;
  int*   cntn = (int*)(base + o);   o += (size_t)NN * 4;
  int*   cntb = (int*)(base + o);   o += (size_t)BB * 4;   // contiguous with cntn
  int*   offn = (int*)(base + o);   o += (size_t)(NN + 4) * 4;
  int*   offb = (int*)(base + o);   o += (size_t)(BB + 4) * 4;
  int*   curn = (int*)(base + o);   o += (size_t)NN * 4;
  int*   curb = (int*)(base + o);   o += (size_t)BB * 4;

  hipMemsetAsync(cntn, 0, (size_t)(NN + BB) * 4, stream);

  kM<<<512, 256, 0, stream>>>(W2, W3, linW, Bth, Btl);
  kEncCount<<<NT + (EE + 255) / 256, 256, 0, stream>>>(Xf, Xs, W1, h,
                                                       edge_dst, bassign, cntn, cntb);
  kScan<<<1, 1024, 0, stream>>>(cntn, offn, curn, cntb, offb, curb);
  kScatter<<<(EE + 255) / 256, 256, 0, stream>>>(edge_src, edge_dst, edge_w, bassign,
                                                 curn, curb, ssrc, swt, snode);
  for (int d = 0; d < DEPTH; d++) {
    kAgg<<<NN + BB, 256, 0, stream>>>(h, offn, ssrc, swt, offb, snode, hnv);
    kUpdM<<<dim3((NT + TRU - 1) / TRU, DD / TCU), 256, 0, stream>>>(h, hnv, Bth, Btl, linB, htmp);
    kNorm<<<NT, 256, 0, stream>>>(htmp, h);
  }
  kDec<<<BB, 256, 0, stream>>>(h, aidx, W4, W5, Q);
}

// Round 4
// 480.137 us; speedup vs baseline: 1.6966x; 1.0643x over previous
//
#include <hip/hip_runtime.h>

#define NN 20000
#define EE 320000
#define BB 64
#define DD 256
#define DEPTH 3
#define NT (NN + BB)   // h rows + hs rows appended (NT = 20064 = 32*627 = 4*5016)

typedef __attribute__((ext_vector_type(8))) short short8;
typedef __attribute__((ext_vector_type(4))) float floatx4;

// ---------------------------------------------------------------- bf16 split helpers
__device__ __forceinline__ short f2bf(float x) {
  union { float f; unsigned u; } v; v.f = x;
  unsigned r = v.u + 0x7fffu + ((v.u >> 16) & 1u);  // RNE
  return (short)(r >> 16);
}
__device__ __forceinline__ float bf2f(short s) {
  union { unsigned u; float f; } v; v.u = ((unsigned)(unsigned short)s) << 16;
  return v.f;
}

// ---------------------------------------------------------------- reductions
__device__ __forceinline__ float blockSum256(float v, float* tmp) {
  #pragma unroll
  for (int o = 32; o > 0; o >>= 1) v += __shfl_down(v, o, 64);
  if ((threadIdx.x & 63) == 0) tmp[threadIdx.x >> 6] = v;
  __syncthreads();
  float r = tmp[0] + tmp[1] + tmp[2] + tmp[3];
  __syncthreads();
  return r;
}

// ---------------------------------------------------------------- M2/M3 -> split transposed B
// M2 = W2 @ linW[0:256,:], M3 = W3 @ linW[256:512,:]
// B'[k][n]: rows 0..255 = M2, 256..511 = M3. Stored as Bt_hi/lo[n][k] bf16 [256][512].
__global__ __launch_bounds__(256) void kM(const float* __restrict__ W2,
                                          const float* __restrict__ W3,
                                          const float* __restrict__ linW,
                                          short* __restrict__ Bth,
                                          short* __restrict__ Btl) {
  int i = blockIdx.x & 255;
  bool second = blockIdx.x >= 256;
  const float* W = second ? W3 : W2;
  const float* L = linW + (second ? DD * DD : 0);
  int j = threadIdx.x;
  float acc = 0.f;
  #pragma unroll 4
  for (int k = 0; k < DD; k++) acc = fmaf(W[i * DD + k], L[k * DD + j], acc);
  short hi = f2bf(acc);
  short lo = f2bf(acc - bf2f(hi));
  int kk = second ? (DD + i) : i;
  Bth[(size_t)j * 512 + kk] = hi;
  Btl[(size_t)j * 512 + kk] = lo;
}

// ---------------------------------------------------------------- count (first) + encode (wave-per-row)
#define NCB ((EE + 255) / 256)   // 1250 count blocks, scheduled first
__global__ __launch_bounds__(256) void kEncCount(const float* __restrict__ X,
                                                 const float* __restrict__ Xs,
                                                 const float* __restrict__ W1,
                                                 float* __restrict__ h,
                                                 const int* __restrict__ dst,
                                                 const int* __restrict__ bassign,
                                                 int* cntn, int* cntb) {
  int bid = blockIdx.x, j = threadIdx.x;
  if (bid < NCB) {
    int t = bid * 256 + j;
    if (t < EE) atomicAdd(&cntn[dst[t]], 1);
    if (t < NN) atomicAdd(&cntb[bassign[t]], 1);
  } else {
    int r = (bid - NCB) * 4 + (j >> 6);     // wave-per-row
    int lane = j & 63, c0 = lane * 4;
    const float* x = (r < NN) ? (X + (size_t)r * 2) : (Xs + (size_t)(r - NN) * 2);
    float x0 = x[0], x1 = x[1];
    float4 wa = *(const float4*)(W1 + c0);
    float4 wb = *(const float4*)(W1 + DD + c0);
    float4 v;
    v.x = fmaxf(fmaf(x0, wa.x, x1 * wb.x), 0.f);
    v.y = fmaxf(fmaf(x0, wa.y, x1 * wb.y), 0.f);
    v.z = fmaxf(fmaf(x0, wa.z, x1 * wb.z), 0.f);
    v.w = fmaxf(fmaf(x0, wa.w, x1 * wb.w), 0.f);
    float ss = v.x * v.x + v.y * v.y + v.z * v.z + v.w * v.w;
    #pragma unroll
    for (int o = 1; o < 64; o <<= 1) ss += __shfl_xor(ss, o, 64);
    float inv = 1.f / fmaxf(sqrtf(ss), 1e-12f);
    v.x *= inv; v.y *= inv; v.z *= inv; v.w *= inv;
    *(float4*)(h + (size_t)r * DD + c0) = v;
  }
}

// ---------------------------------------------------------------- CSR scan
__global__ __launch_bounds__(1024) void kScan(const int* __restrict__ cntn,
                                              int* offn, int* curn,
                                              const int* __restrict__ cntb,
                                              int* offb, int* curb) {
  __shared__ int sums[1024];
  int t = threadIdx.x;
  const int CH = 20;  // 1024*20 = 20480 >= NN
  int base = t * CH;
  int local[CH];
  int s = 0;
  #pragma unroll
  for (int i = 0; i < CH; i++) {
    int idx = base + i;
    int v = (idx < NN) ? cntn[idx] : 0;
    local[i] = s;
    s += v;
  }
  sums[t] = s;
  __syncthreads();
  for (int o = 1; o < 1024; o <<= 1) {
    int x = (t >= o) ? sums[t - o] : 0;
    __syncthreads();
    sums[t] += x;
    __syncthreads();
  }
  int excl = sums[t] - s;
  #pragma unroll
  for (int i = 0; i < CH; i++) {
    int idx = base + i;
    if (idx < NN) {
      int o = excl + local[i];
      offn[idx] = o;
      curn[idx] = o;
    }
  }
  if (t == 1023) offn[NN] = sums[1023];
  // batch offsets: 64-lane shuffle scan (first wave)
  if (t < 64) {
    int v = cntb[t];
    int incl = v;
    #pragma unroll
    for (int o = 1; o < 64; o <<= 1) {
      int x = __shfl_up(incl, o, 64);
      if (t >= o) incl += x;
    }
    int excl2 = incl - v;
    offb[t] = excl2;
    curb[t] = excl2;
    if (t == 63) offb[BB] = incl;
  }
}

__global__ __launch_bounds__(256) void kScatter(const int* __restrict__ src,
                                                const int* __restrict__ dst,
                                                const float* __restrict__ w,
                                                const int* __restrict__ bassign,
                                                int* curn, int* curb,
                                                int* ssrc, float* sw, int* snode) {
  int t = blockIdx.x * 256 + threadIdx.x;
  if (t < EE) {
    int d = dst[t];
    int p = atomicAdd(&curn[d], 1);
    ssrc[p] = src[t];
    sw[p] = w[t];
  }
  if (t < NN) {
    int b = bassign[t];
    int p = atomicAdd(&curb[b], 1);
    snode[p] = t;
  }
}

// ---------------------------------------------------------------- aggregation
// hnv rows 0..NN-1: edge aggregation; rows NN..NN+BB-1: batch aggregation.
__global__ __launch_bounds__(256) void kAgg(const float* __restrict__ h,
                                            const int* __restrict__ offn,
                                            const int* __restrict__ ssrc,
                                            const float* __restrict__ sw,
                                            const int* __restrict__ offb,
                                            const int* __restrict__ snode,
                                            float* __restrict__ hnv) {
  int bid = blockIdx.x, j = threadIdx.x;
  if (bid < BB) {  // batch rows first (longest blocks scheduled early)
    int b = bid;
    int s = offb[b], e = offb[b + 1];
    float acc = 0.f;
    int i = s;
    for (; i + 3 < e; i += 4) {
      int n0 = snode[i], n1 = snode[i + 1], n2 = snode[i + 2], n3 = snode[i + 3];
      float v0 = h[(size_t)n0 * DD + j];
      float v1 = h[(size_t)n1 * DD + j];
      float v2 = h[(size_t)n2 * DD + j];
      float v3 = h[(size_t)n3 * DD + j];
      acc += (v0 + v1) + (v2 + v3);
    }
    for (; i < e; i++) acc += h[(size_t)snode[i] * DD + j];
    hnv[(size_t)(NN + b) * DD + j] = acc;
  } else {
    int n = bid - BB;
    int s = offn[n], e = offn[n + 1];
    float acc = 0.f;
    int i = s;
    for (; i + 3 < e; i += 4) {
      int n0 = ssrc[i], n1 = ssrc[i + 1], n2 = ssrc[i + 2], n3 = ssrc[i + 3];
      float w0 = sw[i], w1 = sw[i + 1], w2 = sw[i + 2], w3 = sw[i + 3];
      float v0 = h[(size_t)n0 * DD + j];
      float v1 = h[(size_t)n1 * DD + j];
      float v2 = h[(size_t)n2 * DD + j];
      float v3 = h[(size_t)n3 * DD + j];
      acc += w0 * v0 + w1 * v1 + w2 * v2 + w3 * v3;
    }
    for (; i < e; i++) acc += sw[i] * h[(size_t)ssrc[i] * DD + j];
    hnv[(size_t)n * DD + j] = acc;
  }
}

// ---------------------------------------------------------------- MFMA dual-GEMM + fused l2norm
// hOut[r,:] = l2norm( relu( sum_k A'[r,k]*B'[k,c] + lb[c] ) ), A' = [h | hnv] (K=512).
// Tile: 32 rows x 256 cols (full width) per block; 4 waves of 32x64; grid = 627 (exact).
#define TRU 32
#define KC 32
__global__ __launch_bounds__(256) void kUpdM(const float* __restrict__ A,
                                             const float* __restrict__ Av,
                                             const short* __restrict__ Bth,
                                             const short* __restrict__ Btl,
                                             const float* __restrict__ lb,
                                             float* __restrict__ out) {
  __shared__ __align__(16) short Ah[TRU][KC];
  __shared__ __align__(16) short Al[TRU][KC];
  __shared__ __align__(16) short Bh[DD][KC];
  __shared__ __align__(16) short Bl[DD][KC];
  __shared__ float ssq[4][TRU];
  const int t = threadIdx.x;
  const int rb = blockIdx.x * TRU;
  const int wid = t >> 6;
  const int lane = t & 63;
  const int wc = wid * 64;         // wave col offset (4 waves cover 256 cols)
  const int m16 = lane & 15;
  const int kg = lane >> 4;        // 0..3

  floatx4 acc[2][4];
  #pragma unroll
  for (int ct = 0; ct < 4; ct++) {
    float b = lb[wc + ct * 16 + m16];
    #pragma unroll
    for (int rt = 0; rt < 2; rt++) acc[rt][ct] = (floatx4){b, b, b, b};
  }

  for (int kc = 0; kc < 512 / KC; ++kc) {
    const int k0 = kc * KC;
    const float* src = (k0 < DD) ? (A + k0) : (Av + (k0 - DD));
    // ---- stage A (fp32 -> hi/lo bf16), 32 rows x 32 k = 256 float4 (1/thread)
    {
      int r = t >> 3;              // 0..31
      int q = t & 7;               // float4 index within row
      float4 v = *(const float4*)(src + (size_t)(rb + r) * DD + q * 4);
      short s0 = f2bf(v.x), s1 = f2bf(v.y), s2 = f2bf(v.z), s3 = f2bf(v.w);
      short l0 = f2bf(v.x - bf2f(s0)), l1 = f2bf(v.y - bf2f(s1));
      short l2 = f2bf(v.z - bf2f(s2)), l3 = f2bf(v.w - bf2f(s3));
      uint2 whi, wlo;
      whi.x = (unsigned short)s0 | ((unsigned)(unsigned short)s1 << 16);
      whi.y = (unsigned short)s2 | ((unsigned)(unsigned short)s3 << 16);
      wlo.x = (unsigned short)l0 | ((unsigned)(unsigned short)l1 << 16);
      wlo.y = (unsigned short)l2 | ((unsigned)(unsigned short)l3 << 16);
      *(uint2*)&Ah[r][q * 4] = whi;
      *(uint2*)&Al[r][q * 4] = wlo;
    }
    // ---- stage B (pre-split bf16, straight copy), 256 n x 32 k per plane
    #pragma unroll
    for (int it = 0; it < 4; ++it) {
      int idx = t + it * 256;      // 0..1023
      int n = idx >> 2;            // 0..255
      int sg = idx & 3;            // 16B segment
      *(uint4*)&Bh[n][sg * 8] = *((const uint4*)(Bth + (size_t)n * 512 + k0) + sg);
      *(uint4*)&Bl[n][sg * 8] = *((const uint4*)(Btl + (size_t)n * 512 + k0) + sg);
    }
    __syncthreads();
    // ---- fragments + MFMA
    short8 af[2], al_[2], bf_[4], bl_[4];
    #pragma unroll
    for (int rt = 0; rt < 2; rt++) {
      af[rt]  = *(const short8*)&Ah[rt * 16 + m16][kg * 8];
      al_[rt] = *(const short8*)&Al[rt * 16 + m16][kg * 8];
    }
    #pragma unroll
    for (int ct = 0; ct < 4; ct++) {
      bf_[ct] = *(const short8*)&Bh[wc + ct * 16 + m16][kg * 8];
      bl_[ct] = *(const short8*)&Bl[wc + ct * 16 + m16][kg * 8];
    }
    #pragma unroll
    for (int rt = 0; rt < 2; rt++)
      #pragma unroll
      for (int ct = 0; ct < 4; ct++) {
        acc[rt][ct] = __builtin_amdgcn_mfma_f32_16x16x32_bf16(af[rt], bf_[ct], acc[rt][ct], 0, 0, 0);
        acc[rt][ct] = __builtin_amdgcn_mfma_f32_16x16x32_bf16(af[rt], bl_[ct], acc[rt][ct], 0, 0, 0);
        acc[rt][ct] = __builtin_amdgcn_mfma_f32_16x16x32_bf16(al_[rt], bf_[ct], acc[rt][ct], 0, 0, 0);
      }
    __syncthreads();
  }
  // ---- epilogue: relu + row l2norm + store (C/D: col=lane&15, row=(lane>>4)*4+reg)
  float p[2][4];
  #pragma unroll
  for (int rt = 0; rt < 2; rt++)
    #pragma unroll
    for (int reg = 0; reg < 4; reg++) {
      float s = 0.f;
      #pragma unroll
      for (int ct = 0; ct < 4; ct++) {
        float x = fmaxf(acc[rt][ct][reg], 0.f);
        s = fmaf(x, x, s);
      }
      p[rt][reg] = s;
    }
  #pragma unroll
  for (int o = 1; o < 16; o <<= 1)
    #pragma unroll
    for (int rt = 0; rt < 2; rt++)
      #pragma unroll
      for (int reg = 0; reg < 4; reg++)
        p[rt][reg] += __shfl_xor(p[rt][reg], o, 64);
  if (m16 == 0) {
    #pragma unroll
    for (int rt = 0; rt < 2; rt++)
      #pragma unroll
      for (int reg = 0; reg < 4; reg++)
        ssq[wid][rt * 16 + kg * 4 + reg] = p[rt][reg];
  }
  __syncthreads();
  #pragma unroll
  for (int rt = 0; rt < 2; rt++) {
    #pragma unroll
    for (int reg = 0; reg < 4; reg++) {
      int row = rt * 16 + kg * 4 + reg;
      float ss = ssq[0][row] + ssq[1][row] + ssq[2][row] + ssq[3][row];
      float inv = 1.f / fmaxf(sqrtf(ss), 1e-12f);
      #pragma unroll
      for (int ct = 0; ct < 4; ct++) {
        int col = wc + ct * 16 + m16;
        out[(size_t)(rb + row) * DD + col] = fmaxf(acc[rt][ct][reg], 0.f) * inv;
      }
    }
  }
}

// ---------------------------------------------------------------- decode
__global__ __launch_bounds__(256) void kDec(const float* __restrict__ h,
                                            const int* __restrict__ aidx,
                                            const float* __restrict__ W4,
                                            const float* __restrict__ W5,
                                            float* __restrict__ Q) {
  __shared__ float tmp[4];
  int b = blockIdx.x, j = threadIdx.x;
  float s = blockSum256(h[(size_t)(NN + b) * DD + j] * W4[j], tmp);
  int a = aidx[b];
  float za = h[(size_t)a * DD + j];
  float q = blockSum256(fmaxf(za * s, 0.f) * W5[j], tmp);
  if (j == 0) Q[b] = q;
}

// ---------------------------------------------------------------- launcher
extern "C" void kernel_launch(void* const* d_in, const int* in_sizes, int n_in,
                              void* d_out, int out_size, void* d_ws, size_t ws_size,
                              hipStream_t stream) {
  (void)in_sizes; (void)n_in; (void)out_size; (void)ws_size;
  const int*   edge_src = (const int*)d_in[0];
  const int*   edge_dst = (const int*)d_in[1];
  const float* edge_w   = (const float*)d_in[2];
  const int*   bassign  = (const int*)d_in[3];
  const int*   aidx     = (const int*)d_in[4];
  const float* Xf       = (const float*)d_in[5];
  const float* Xs       = (const float*)d_in[6];
  const float* W1       = (const float*)d_in[7];
  const float* W2       = (const float*)d_in[8];
  const float* W3       = (const float*)d_in[9];
  const float* linW     = (const float*)d_in[10];
  const float* linB     = (const float*)d_in[11];
  const float* W4       = (const float*)d_in[12];
  const float* W5       = (const float*)d_in[13];
  float* Q = (float*)d_out;

  char* base = (char*)d_ws;
  const size_t NB = (size_t)NT * DD * 4;   // rows include hs
  float* hA   = (float*)(base);
  float* hnv  = (float*)(base + NB);
  float* hB   = (float*)(base + 2 * NB);
  size_t o = 3 * NB;
  short* Bth  = (short*)(base + o); o += (size_t)DD * 512 * 2;
  short* Btl  = (short*)(base + o); o += (size_t)DD * 512 * 2;
  int*   ssrc = (int*)(base + o);   o += (size_t)EE * 4;
  float* swt  = (float*)(base + o); o += (size_t)EE * 4;
  int*   snode= (int*)(base + o);   o += (size_t)NN * 4;
  int*   cntn = (int*)(base + o);   o += (size_t)NN * 4;
  int*   cntb = (int*)(base + o);   o += (size_t)BB * 4;   // contiguous with cntn
  int*   offn = (int*)(base + o);   o += (size_t)(NN + 4) * 4;
  int*   offb = (int*)(base + o);   o += (size_t)(BB + 4) * 4;
  int*   curn = (int*)(base + o);   o += (size_t)NN * 4;
  int*   curb = (int*)(base + o);   o += (size_t)BB * 4;

  hipMemsetAsync(cntn, 0, (size_t)(NN + BB) * 4, stream);

  kM<<<512, 256, 0, stream>>>(W2, W3, linW, Bth, Btl);
  kEncCount<<<NCB + NT / 4, 256, 0, stream>>>(Xf, Xs, W1, hA,
                                              edge_dst, bassign, cntn, cntb);
  kScan<<<1, 1024, 0, stream>>>(cntn, offn, curn, cntb, offb, curb);
  kScatter<<<(EE + 255) / 256, 256, 0, stream>>>(edge_src, edge_dst, edge_w, bassign,
                                                 curn, curb, ssrc, swt, snode);
  float* hc = hA;
  float* hn = hB;
  for (int d = 0; d < DEPTH; d++) {
    kAgg<<<NN + BB, 256, 0, stream>>>(hc, offn, ssrc, swt, offb, snode, hnv);
    kUpdM<<<NT / TRU, 256, 0, stream>>>(hc, hnv, Bth, Btl, linB, hn);
    float* sw2 = hc; hc = hn; hn = sw2;
  }
  kDec<<<BB, 256, 0, stream>>>(hc, aidx, W4, W5, Q);
}